// Round 11
// baseline (1710.890 us; speedup 1.0000x reference)
//
#include <hip/hip_runtime.h>
#include <math.h>

#define N_CELLS 8192
#define DIM 512
#define TILE 128
#define RT 128            // rows per P1/P3 block
#define CS 1024           // cols per P1/P3 block
#define NCB (N_CELLS / CS)   // 8 col-spans
#define NLISTS (NCB * 2)     // 16 candidate lists per row
#define EBS 128              // eb row stride (64 KB total = static LDS max)

typedef float f32x4 __attribute__((ext_vector_type(4)));
typedef _Float16 f16x8 __attribute__((ext_vector_type(8)));

#define AS1U(p) ((const __attribute__((address_space(1))) unsigned int*)(p))
#define AS3U(p) ((__attribute__((address_space(3))) unsigned int*)(p))

// ---------- helpers: order-preserving float<->uint key ----------
__device__ __forceinline__ unsigned fkey(float f) {
    unsigned u = __float_as_uint(f);
    return (u & 0x80000000u) ? ~u : (u | 0x80000000u);
}
__device__ __forceinline__ float finv(unsigned k) {
    unsigned u = (k & 0x80000000u) ? (k ^ 0x80000000u) : ~k;
    return __uint_as_float(u);
}

// ---------- kernel A: squared norms (exact fp32) + zero output ----------
__global__ __launch_bounds__(256) void norms_kernel(const float* __restrict__ E,
                                                    float* __restrict__ norms,
                                                    float* __restrict__ out) {
    if (blockIdx.x == 0 && threadIdx.x == 0) out[0] = 0.0f;
    const int wave = threadIdx.x >> 6, lane = threadIdx.x & 63;
    const int row = blockIdx.x * 4 + wave;
    const float4* e4 = (const float4*)(E + (size_t)row * DIM);
    float4 a = e4[lane], b = e4[lane + 64];
    float s = a.x*a.x + a.y*a.y + a.z*a.z + a.w*a.w
            + b.x*b.x + b.y*b.y + b.z*b.z + b.w*b.w;
    #pragma unroll
    for (int off = 32; off > 0; off >>= 1) s += __shfl_down(s, off, 64);
    if (lane == 0) norms[row] = s;
}

// ---------- kernel A2: fp32 -> fp16 (RTNE) ----------
__global__ __launch_bounds__(256) void convert_f16_kernel(const float* __restrict__ E,
                                                          unsigned short* __restrict__ Ef) {
    const int idx = (blockIdx.x * 256 + threadIdx.x) * 8;
    float4 v0 = *(const float4*)(E + idx);
    float4 v1 = *(const float4*)(E + idx + 4);
    f16x8 h;
    h[0] = (_Float16)v0.x; h[1] = (_Float16)v0.y; h[2] = (_Float16)v0.z; h[3] = (_Float16)v0.w;
    h[4] = (_Float16)v1.x; h[5] = (_Float16)v1.y; h[6] = (_Float16)v1.z; h[7] = (_Float16)v1.w;
    *(f16x8*)(Ef + idx) = h;
}

// ---------- shared GEMM tile core (P1/P3): compute one 128x128 D-tile into eb.
// eb stride 128 (64 KB). Staging (BK=64: A 16KB + B 16KB) unions with eb[0,32KB).
// Epilogue tn-order staggered per quad -> 2-way LDS write aliasing (free).
__device__ __forceinline__ void gemm_tile_to_eb(const unsigned short* __restrict__ Ef,
                                                const float* __restrict__ norms,
                                                float* eb, const float ni[16],
                                                int arow, int brow,
                                                int t, int lane, int wr, int wc) {
    char* smem = (char*)eb;
    const unsigned short* Ah = (const unsigned short*)smem;
    const unsigned short* Bh = (const unsigned short*)(smem + 16384);
    const int srow = t & 127, skc = t >> 7;
    const int kg = lane >> 4, fr = lane & 15;
    const int quad = lane >> 4;

    f32x4 acc[4][4];
    #pragma unroll
    for (int a = 0; a < 4; a++)
        #pragma unroll
        for (int b = 0; b < 4; b++)
            acc[a][b] = (f32x4){0.f, 0.f, 0.f, 0.f};

    for (int k0 = 0; k0 < DIM; k0 += 64) {
        __syncthreads();   // eb/staging free (prev scan done / frag reads done)
        {
            const size_t ga = (size_t)(arow + srow) * DIM + k0;
            const size_t gb = (size_t)(brow + srow) * DIM + k0;
            #pragma unroll
            for (int j = 0; j < 4; j++) {
                __builtin_amdgcn_global_load_lds(AS1U(Ef + ga + (size_t)(2*j + skc) * 8),
                                                 AS3U(smem + j*4096 + t*16), 16, 0, 0);
                __builtin_amdgcn_global_load_lds(AS1U(Ef + gb + (size_t)(2*j + skc) * 8),
                                                 AS3U(smem + 16384 + j*4096 + t*16), 16, 0, 0);
            }
        }
        __syncthreads();
        #pragma unroll
        for (int h = 0; h < 2; h++) {
            const int kc = kg + 4*h;
            f16x8 af[4], bf[4];
            #pragma unroll
            for (int tm = 0; tm < 4; tm++)
                af[tm] = *(const f16x8*)(Ah + (size_t)(kc*128 + wr*64 + tm*16 + fr) * 8);
            #pragma unroll
            for (int tn = 0; tn < 4; tn++)
                bf[tn] = *(const f16x8*)(Bh + (size_t)(kc*128 + wc*64 + tn*16 + fr) * 8);
            #pragma unroll
            for (int tm = 0; tm < 4; tm++)
                #pragma unroll
                for (int tn = 0; tn < 4; tn++)
                    acc[tm][tn] = __builtin_amdgcn_mfma_f32_16x16x32_f16(af[tm], bf[tn], acc[tm][tn], 0, 0, 0);
        }
    }
    __syncthreads();   // all waves' frag reads done before eb overwrite

    // epilogue: C/D layout col=lane&15(+16*tn+64*wc), row=quad*4+r(+16*tm+64*wr)
    {
        const int colb = wc*64 + (lane & 15);
        const int rowb = wr*64 + quad*4;
        #pragma unroll
        for (int tn0 = 0; tn0 < 4; tn0++) {
            const int tn = (tn0 + quad) & 3;           // stagger banks per quad
            const int col = colb + tn*16;
            const float nj = norms[brow + col];
            #pragma unroll
            for (int tm = 0; tm < 4; tm++) {
                #pragma unroll
                for (int r = 0; r < 4; r++) {
                    const int rloc = rowb + tm*16 + r;
                    float d = ni[tm*4+r] + nj - 2.0f*acc[tm][tn][r];
                    if (arow + rloc == brow + col) d += 1e10f;
                    eb[rloc*EBS + col] = d;
                }
            }
        }
    }
    __syncthreads();   // eb complete; scan may read
}

// ---------- P1: GEMM sweep + per-(row,half) exact top-15 candidates ----------
__global__ void p1_kernel(const unsigned short* __restrict__ Ef,
                          const float* __restrict__ norms,
                          float* __restrict__ cand) {
    __shared__ __align__(16) float eb[RT * EBS];     // 64 KB (union w/ staging)
    const int t = threadIdx.x;
    const int lane = t & 63, w = t >> 6, wr = w >> 1, wc = w & 1;
    const int arow = blockIdx.y * RT;
    const int cb = blockIdx.x;
    const int selRow = t & 127, selHalf = t >> 7;
    const int rot = selRow & 63;

    float ni[16];
    #pragma unroll
    for (int tm = 0; tm < 4; tm++)
        #pragma unroll
        for (int r = 0; r < 4; r++)
            ni[tm*4+r] = norms[arow + wr*64 + tm*16 + (lane>>4)*4 + r];

    float lst[15];
    #pragma unroll
    for (int k = 0; k < 15; k++) lst[k] = 3.0e38f;

    for (int ct = 0; ct < CS/TILE; ct++) {
        const int brow = cb * CS + ct * TILE;
        gemm_tile_to_eb(Ef, norms, eb, ni, arow, brow, t, lane, wr, wc);
        // scan: rotated col order -> 2-way bank aliasing (free)
        const float* rowp = &eb[selRow*EBS + selHalf*64];
        #pragma unroll 8
        for (int c = 0; c < 64; c++) {
            float v = rowp[(rot + c) & 63];
            if (v < lst[14]) {
                #pragma unroll
                for (int k = 0; k < 15; k++) {
                    float lo2 = fminf(lst[k], v);
                    v = fmaxf(lst[k], v);
                    lst[k] = lo2;
                }
            }
        }
        // next tile's first barrier protects eb
    }
    float* dst = cand + ((size_t)(arow + selRow) * NCB + cb) * 30 + selHalf * 15;
    #pragma unroll
    for (int k = 0; k < 15; k++) dst[k] = lst[k];
}

// ---------- P2: exact kth + dmin per row from 240 candidates ----------
__global__ __launch_bounds__(256) void p2_kernel(const float* __restrict__ cand,
                                                 float* __restrict__ kthA,
                                                 float* __restrict__ dminA) {
    const int lane = threadIdx.x & 63;
    const int row = blockIdx.x * 4 + (threadIdx.x >> 6);
    const float* cp = cand + (size_t)row * (NLISTS * 15);   // 240
    unsigned key[4];
    float mn = 3.0e38f;
    #pragma unroll
    for (int s = 0; s < 4; s++) {
        const int idx = s * 64 + lane;
        if (idx < NLISTS * 15) { float v = cp[idx]; key[s] = fkey(v); mn = fminf(mn, v); }
        else key[s] = 0xFFFFFFFFu;
    }
    #pragma unroll
    for (int off = 32; off > 0; off >>= 1) mn = fminf(mn, __shfl_xor(mn, off, 64));
    unsigned lo = fkey(mn), hi = 0xFFFFFFFEu;
    int it = 0;
    while (lo < hi && it < 34) {
        it++;
        const unsigned mid = lo + ((hi - lo) >> 1);
        int c = 0;
        #pragma unroll
        for (int s = 0; s < 4; s++) c += (key[s] <= mid) ? 1 : 0;
        #pragma unroll
        for (int off = 32; off > 0; off >>= 1) c += __shfl_xor(c, off, 64);
        if (c >= 15) hi = mid; else lo = mid + 1;
    }
    if (lane == 0) { kthA[row] = finv(hi); dminA[row] = mn; }
}

// ---------- P3: GEMM sweep again + masked-softmax partial sums ----------
__global__ void p3_kernel(const unsigned short* __restrict__ Ef,
                          const float* __restrict__ norms,
                          const int* __restrict__ labels,
                          const float* __restrict__ kthA,
                          const float* __restrict__ dminA,
                          float4* __restrict__ partial) {
    __shared__ __align__(16) float eb[RT * EBS];     // 64 KB (union w/ staging)
    const int t = threadIdx.x;
    const int lane = t & 63, w = t >> 6, wr = w >> 1, wc = w & 1;
    const int arow = blockIdx.y * RT;
    const int cb = blockIdx.x;
    const int selRow = t & 127, selHalf = t >> 7;
    const int rot = selRow & 63;

    float ni[16];
    #pragma unroll
    for (int tm = 0; tm < 4; tm++)
        #pragma unroll
        for (int r = 0; r < 4; r++)
            ni[tm*4+r] = norms[arow + wr*64 + tm*16 + (lane>>4)*4 + r];

    const int grow = arow + selRow;
    const float dmin = dminA[grow];
    const float kth  = kthA[grow];
    const float C = __expf(dmin - kth);
    float z = 0.f, s0 = 0.f, s1 = 0.f, s2 = 0.f;

    for (int ct = 0; ct < CS/TILE; ct++) {
        const int brow = cb * CS + ct * TILE;
        gemm_tile_to_eb(Ef, norms, eb, ni, arow, brow, t, lane, wr, wc);
        const float* rowp = &eb[selRow*EBS + selHalf*64];
        const int gcol0 = brow + selHalf*64;
        #pragma unroll 8
        for (int c = 0; c < 64; c++) {
            const int cc = (rot + c) & 63;
            const float d = rowp[cc];
            const int lab = labels[gcol0 + cc];
            const float wv = __expf(dmin - d);
            const float p = wv * wv * __frcp_rn(fmaxf(wv + C, 1e-37f));  // w*sigmoid(kth-d), NaN-safe
            z  += wv;
            s0 += (lab == 0) ? p : 0.f;
            s1 += (lab == 1) ? p : 0.f;
            s2 += (lab == 2) ? p : 0.f;
        }
    }
    partial[(size_t)grow * NLISTS + cb * 2 + selHalf] = (float4){z, s0, s1, s2};
}

// ---------- P4: reduce partials -> entropy -> scalar ----------
__global__ __launch_bounds__(256) void p4_kernel(const float4* __restrict__ partial,
                                                 float* __restrict__ out) {
    const int row = blockIdx.x * 256 + threadIdx.x;
    const int lane = threadIdx.x & 63;
    const float4* pp = partial + (size_t)row * NLISTS;
    float Z = 0.f, S0 = 0.f, S1 = 0.f, S2 = 0.f;
    #pragma unroll
    for (int i = 0; i < NLISTS; i++) {
        float4 v = pp[i];
        Z += v.x; S0 += v.y; S1 += v.z; S2 += v.w;
    }
    const float ssum = S0 + S1 + S2;
    const float denom = ssum + 1e-8f * Z;
    const float q0 = S0/denom, q1 = S1/denom, q2 = S2/denom;
    const float H = -(q0*logf(q0+1e-8f) + q1*logf(q1+1e-8f) + q2*logf(q2+1e-8f));
    float contrib = -(H / (logf(3.0f) + 1e-8f)) * (1.0f / N_CELLS);
    #pragma unroll
    for (int off = 32; off > 0; off >>= 1) contrib += __shfl_down(contrib, off, 64);
    if (lane == 0) atomicAdd(out, contrib);
}

// ---------- fallback pieces (tiny-ws only): block-wide search + fused fp32 ----------
template<int NT>
__device__ __forceinline__ void finish_row(const float* rowb,
                                           float lst[15],
                                           const int* __restrict__ labels,
                                           float* __restrict__ out) {
    constexpr int WAVES = NT / 64;
    __shared__ float w0s[WAVES], w14s[WAVES];
    __shared__ int cnt;
    __shared__ float zz[WAVES], r0s[WAVES], r1s[WAVES], r2s[WAVES];

    const int t = threadIdx.x;
    const int lane = t & 63, wave = t >> 6;

    float m0 = lst[0], m14 = lst[14];
    #pragma unroll
    for (int off = 32; off > 0; off >>= 1) {
        m0  = fminf(m0,  __shfl_down(m0,  off, 64));
        m14 = fminf(m14, __shfl_down(m14, off, 64));
    }
    if (lane == 0) { w0s[wave] = m0; w14s[wave] = m14; }
    __syncthreads();
    float dmin = w0s[0], ub = w14s[0];
    #pragma unroll
    for (int i = 1; i < WAVES; i++) { dmin = fminf(dmin, w0s[i]); ub = fminf(ub, w14s[i]); }

    unsigned lo = fkey(dmin), hi = fkey(ub);
    int iter = 0;
    while (lo < hi && iter < 34) {
        iter++;
        const unsigned mid = lo + ((hi - lo) >> 1);
        const float fmid = finv(mid);
        int c = 0;
        #pragma unroll
        for (int k = 0; k < 15; k++) c += (lst[k] <= fmid) ? 1 : 0;
        #pragma unroll
        for (int off = 32; off > 0; off >>= 1) c += __shfl_down(c, off, 64);
        __syncthreads();
        if (t == 0) cnt = 0;
        __syncthreads();
        if (lane == 0) atomicAdd(&cnt, c);
        __syncthreads();
        const int total = cnt;
        if (total >= 15) hi = mid; else lo = mid + 1;
    }
    const float kth = finv(hi);

    const float4* rb4 = (const float4*)rowb;
    const int4* lb4 = (const int4*)labels;
    float z = 0.f, s0 = 0.f, s1 = 0.f, s2 = 0.f;
    #pragma unroll
    for (int s = 0; s < N_CELLS / (4 * NT); s++) {
        const int idx = s * NT + t;
        const float4 d4 = rb4[idx];
        const int4 l4 = lb4[idx];
        #pragma unroll
        for (int c2 = 0; c2 < 4; c2++) {
            const float d = (c2 == 0) ? d4.x : (c2 == 1) ? d4.y : (c2 == 2) ? d4.z : d4.w;
            const int lab = (c2 == 0) ? l4.x : (c2 == 1) ? l4.y : (c2 == 2) ? l4.z : l4.w;
            const float wv = __expf(dmin - d);
            const float msk = 1.0f / (1.0f + __expf(d - kth));
            const float p = wv * msk;
            z  += wv;
            s0 += (lab == 0) ? p : 0.f;
            s1 += (lab == 1) ? p : 0.f;
            s2 += (lab == 2) ? p : 0.f;
        }
    }
    #pragma unroll
    for (int off = 32; off > 0; off >>= 1) {
        z  += __shfl_down(z,  off, 64);
        s0 += __shfl_down(s0, off, 64);
        s1 += __shfl_down(s1, off, 64);
        s2 += __shfl_down(s2, off, 64);
    }
    if (lane == 0) { zz[wave] = z; r0s[wave] = s0; r1s[wave] = s1; r2s[wave] = s2; }
    __syncthreads();
    if (t == 0) {
        float Z = 0.f, S0 = 0.f, S1 = 0.f, S2 = 0.f;
        #pragma unroll
        for (int i = 0; i < WAVES; i++) { Z += zz[i]; S0 += r0s[i]; S1 += r1s[i]; S2 += r2s[i]; }
        const float ssum = S0 + S1 + S2;
        const float denom = ssum + 1e-8f * Z;
        const float q0 = S0/denom, q1 = S1/denom, q2 = S2/denom;
        const float H = -(q0*logf(q0+1e-8f) + q1*logf(q1+1e-8f) + q2*logf(q2+1e-8f));
        const float contrib = -(H / (logf(3.0f) + 1e-8f)) * (1.0f / N_CELLS);
        atomicAdd(out, contrib);
    }
}

__global__ __launch_bounds__(512) void fused_kernel(const float* __restrict__ E,
                                                    const float* __restrict__ norms,
                                                    const int* __restrict__ labels,
                                                    float* __restrict__ out) {
    __shared__ float rowb[N_CELLS];
    __shared__ float ei[DIM];
    const int i = blockIdx.x;
    const int t = threadIdx.x;

    for (int k = t; k < DIM; k += 512) ei[k] = E[(size_t)i * DIM + k];
    __syncthreads();
    const float ni = norms[i];

    float lst[15];
    #pragma unroll
    for (int k = 0; k < 15; k++) lst[k] = 3.0e38f;

    for (int s = 0; s < N_CELLS / 512; s++) {
        const int j = s * 512 + t;
        const float* ej = E + (size_t)j * DIM;
        float dot = 0.f;
        #pragma unroll 4
        for (int k = 0; k < DIM; k += 4) {
            float4 e4 = *(const float4*)(ej + k);
            dot += ei[k]*e4.x + ei[k+1]*e4.y + ei[k+2]*e4.z + ei[k+3]*e4.w;
        }
        float d = ni + norms[j] - 2.0f * dot;
        if (j == i) d += 1e10f;
        rowb[j] = d;
        float v = d;
        #pragma unroll
        for (int k = 0; k < 15; k++) {
            float lo2 = fminf(lst[k], v);
            v = fmaxf(lst[k], v);
            lst[k] = lo2;
        }
    }
    finish_row<512>(rowb, lst, labels, out);
}

// ---------- launcher ----------
// ws: norms 32KB | Ef 8MB | cand 7.9MB | kth 32KB | dmin 32KB | partial 2MB
// (~18.4 MB total). D is never materialized in HBM. Tiny-ws: fused fallback.
extern "C" void kernel_launch(void* const* d_in, const int* in_sizes, int n_in,
                              void* d_out, int out_size, void* d_ws, size_t ws_size,
                              hipStream_t stream) {
    const float* E = (const float*)d_in[0];
    const int* labels = (const int*)d_in[1];
    float* out = (float*)d_out;

    char* p = (char*)d_ws;
    float* norms = (float*)p;                 p += 32768;
    unsigned short* Ef = (unsigned short*)p;  p += (size_t)N_CELLS * DIM * 2;           // 8 MB
    float* cand = (float*)p;                  p += (size_t)N_CELLS * NLISTS * 15 * 4;   // 7.9 MB
    float* kthA = (float*)p;                  p += (size_t)N_CELLS * 4;
    float* dminA = (float*)p;                 p += (size_t)N_CELLS * 4;
    float4* partial = (float4*)p;             p += (size_t)N_CELLS * NLISTS * 16;       // 2 MB

    const size_t need = (size_t)(p - (char*)d_ws);

    norms_kernel<<<N_CELLS / 4, 256, 0, stream>>>(E, norms, out);

    if (ws_size >= need) {
        convert_f16_kernel<<<(N_CELLS * DIM) / (256 * 8), 256, 0, stream>>>(E, Ef);
        dim3 g(NCB, N_CELLS / RT);   // (8, 64) = 512 blocks
        p1_kernel<<<g, 256, 0, stream>>>(Ef, norms, cand);
        p2_kernel<<<N_CELLS / 4, 256, 0, stream>>>(cand, kthA, dminA);
        p3_kernel<<<g, 256, 0, stream>>>(Ef, norms, labels, kthA, dminA, partial);
        p4_kernel<<<N_CELLS / 256, 256, 0, stream>>>(partial, out);
    } else {
        fused_kernel<<<N_CELLS, 512, 0, stream>>>(E, norms, labels, out);
    }
}